// Round 8
// baseline (236.046 us; speedup 1.0000x reference)
//
#include <hip/hip_runtime.h>

#define NB 32
#define NI 2048
#define NP 16
#define NJ 32
#define ND 32
#define EPSF 1e-7f

typedef __attribute__((ext_vector_type(8))) short bf16x8;
typedef __attribute__((ext_vector_type(16))) float f32x16;
typedef __attribute__((ext_vector_type(4))) float f32x4;

static __device__ __forceinline__ unsigned cvt_pk_bf16(float lo, float hi) {
  unsigned r;
  asm("v_cvt_pk_bf16_f32 %0, %1, %2" : "=v"(r) : "v"(lo), "v"(hi));
  return r;
}

static __device__ __forceinline__ f32x16 mfma_bf16(bf16x8 a, bf16x8 b, f32x16 c) {
  return __builtin_amdgcn_mfma_f32_32x32x16_bf16(a, b, c, 0, 0, 0);
}

// A operand for U^T = W^T(d x p) @ X^T(p x b), one (i,j), from raw f32 W.
// lane l: m = d = l&31, k = p = 8*(l>>5) + e  (e = 0..7)
static __device__ __forceinline__ bf16x8 load_wfrag_f32(const float* __restrict__ W,
                                                        int i, int j, int h, int d) {
  const float* wp = W + (((size_t)i * NJ + j) * NP + h * 8) * ND + d;
  union { unsigned u[4]; bf16x8 v; } wf;
  wf.u[0] = cvt_pk_bf16(wp[0 * ND], wp[1 * ND]);
  wf.u[1] = cvt_pk_bf16(wp[2 * ND], wp[3 * ND]);
  wf.u[2] = cvt_pk_bf16(wp[4 * ND], wp[5 * ND]);
  wf.u[3] = cvt_pk_bf16(wp[6 * ND], wp[7 * ND]);
  return wf.v;
}

// B operand: lane l: k = p = 8*(l>>5)+e, n = b = l&31
static __device__ __forceinline__ bf16x8 load_xfrag(const unsigned short* __restrict__ Xt,
                                                    int i, int b, int h) {
  return *(const bf16x8*)(Xt + ((size_t)i * NB + b) * NP + h * 8);
}

// ---------- prep: inputs[b][i][p] (f32) -> Xt[i][b][p] (bf16) ----------
__global__ __launch_bounds__(256) void kern_prep(const float* __restrict__ in,
                                                 unsigned short* __restrict__ Xt) {
  const int t = blockIdx.x * 256 + threadIdx.x;   // 262144 threads, 4 elems each
  const int rest = t >> 2;                        // b*NI + i
  const int p4 = (t & 3) * 4;
  const int i = rest & (NI - 1);
  const int b = rest >> 11;
  f32x4 x = *(const f32x4*)(in + (size_t)rest * NP + p4);
  uint2 v;
  v.x = cvt_pk_bf16(x[0], x[1]);
  v.y = cvt_pk_bf16(x[2], x[3]);
  *(uint2*)(Xt + ((size_t)i * NB + b) * NP + p4) = v;
}

// ---------- fused: [logits -> softmax ->] weighted partial sum over i-chunk ----
// 1024 threads = 16 waves; wave w owns j = w*2 + t (t=0..1)  [was 8 waves x 4 j:
// halves per-wave accumulator state (~180 -> ~100 VGPR) to lift waves/SIMD 2->4].
// block ch handles i in [ch*ipb, ch*ipb+ipb). part[j][ch][b][d] partials.
// UNIFORM: c = 1/32 (routing iter 0), no logits/softmax needed.
template <bool UNIFORM>
__global__ __launch_bounds__(1024) void kern_fused(const float* __restrict__ W,
                                                   const unsigned short* __restrict__ Xt,
                                                   const float* __restrict__ vsum,
                                                   float* __restrict__ part,
                                                   int ipb, int nch) {
  const int tid = threadIdx.x;
  const int w = tid >> 6;        // 0..15
  const int lane = tid & 63;
  const int b = lane & 31;
  const int h = lane >> 5;
  const int ch = blockIdx.x;

  // register-resident vsum fragment: vs[t][q][e] = vsum[b][j=w*2+t][8q + 4h + e]
  f32x4 vs[2][4];
  if (!UNIFORM) {
#pragma unroll
    for (int t = 0; t < 2; ++t) {
      const int j = w * 2 + t;
#pragma unroll
      for (int q = 0; q < 4; ++q)
        vs[t][q] = *(const f32x4*)(vsum + ((size_t)b * NJ + j) * ND + q * 8 + h * 4);
    }
  }

  f32x16 sacc[2] = {};
  __shared__ float lgt[NJ][33];   // single buffer, 2 barriers per ii (proven structure)

  for (int ii = 0; ii < ipb; ++ii) {
    const int i = ch * ipb + ii;
    const bf16x8 xf = load_xfrag(Xt, i, b, h);
    if (UNIFORM) {
#pragma unroll
      for (int t = 0; t < 2; ++t)
        sacc[t] = mfma_bf16(load_wfrag_f32(W, i, w * 2 + t, h, b), xf, sacc[t]);
    } else {
      f32x16 um[2];
      float lg[2];
#pragma unroll
      for (int t = 0; t < 2; ++t) {
        const int j = w * 2 + t;
        f32x16 z = {};
        um[t] = mfma_bf16(load_wfrag_f32(W, i, j, h, b), xf, z);  // um[r]=U^T[d(r)][b]
        float p = 0.f;
#pragma unroll
        for (int r = 0; r < 16; ++r)
          p += um[t][r] * vs[t][r >> 2][r & 3];   // d(r) = (r&3) + 8*(r>>2) + 4h
        p += __shfl_xor(p, 32);                   // add partner half's 16 d's
        lg[t] = p;
      }
      if (h == 0) {
#pragma unroll
        for (int t = 0; t < 2; ++t) lgt[w * 2 + t][b] = lg[t];
      }
      __syncthreads();
      // per-(b,i) softmax over j (each thread reduces its own b's column)
      float mx = -3.0e38f;
#pragma unroll
      for (int jj = 0; jj < NJ; ++jj) mx = fmaxf(mx, lgt[jj][b]);
      float den = 0.f;
#pragma unroll
      for (int jj = 0; jj < NJ; ++jj) den += expf(lgt[jj][b] - mx);
      const float inv = 1.0f / den;
#pragma unroll
      for (int t = 0; t < 2; ++t) {
        const float c = expf(lg[t] - mx) * inv;
#pragma unroll
        for (int r = 0; r < 16; ++r) sacc[t][r] += c * um[t][r];
      }
      __syncthreads();   // protect lgt before next i overwrites it
    }
  }

#pragma unroll
  for (int t = 0; t < 2; ++t) {
    const int j = w * 2 + t;
#pragma unroll
    for (int r = 0; r < 16; ++r) {
      const float val = UNIFORM ? sacc[t][r] * (1.0f / 32.0f) : sacc[t][r];
      const int d = (r & 3) + 8 * (r >> 2) + 4 * h;
      part[(((size_t)j * nch + ch) * NB + b) * ND + d] = val;
    }
  }
}

// ---------- stage-1 reduce: 32-chunk groups -> part2[j][r][b][d] ----------
__global__ __launch_bounds__(1024) void kern_reduce1(const float* __restrict__ part,
                                                     float* __restrict__ part2,
                                                     int nch, int RG) {
  const int j = blockIdx.x / RG;
  const int r = blockIdx.x % RG;
  const int t = threadIdx.x;
  const int b = t >> 5;
  const int d = t & 31;
  float s = 0.f;
#pragma unroll 4
  for (int c = 0; c < 32; ++c)
    s += part[(((size_t)j * nch + r * 32 + c) * NB + b) * ND + d];
  part2[(((size_t)j * RG + r) * NB + b) * ND + d] = s;
}

// ---------- final reduce + squash + vsum/out ----------
__global__ __launch_bounds__(1024) void kern_squash(const float* __restrict__ part2,
                                                    float* __restrict__ vsum,
                                                    float* __restrict__ out,
                                                    int mode, int RG) {
  const int j = blockIdx.x;
  const int t = threadIdx.x;
  const int b = t >> 5;
  const int d = t & 31;
  float s = 0.f;
  for (int r = 0; r < RG; ++r)
    s += part2[(((size_t)j * RG + r) * NB + b) * ND + d];

  __shared__ float sl[32][33];
  __shared__ float fb[32];
  sl[b][d] = s;
  __syncthreads();
  if (t < 32) {
    float n2 = 0.f;
#pragma unroll
    for (int dd = 0; dd < ND; ++dd) { const float x = sl[t][dd]; n2 += x * x; }
    fb[t] = n2 / ((1.0f + n2) * sqrtf(n2 + EPSF));
  }
  __syncthreads();
  const float v = s * fb[b];
  const int idx = (b * NJ + j) * ND + d;
  if (mode == 0)      vsum[idx] = v;        // iter0: vsum := v0 (never read-before-write)
  else if (mode == 1) vsum[idx] += v;       // iter1: vsum := v0+v1
  else                out[idx] = v;         // iter2: final output [B,J,D]
}

extern "C" void kernel_launch(void* const* d_in, const int* in_sizes, int n_in,
                              void* d_out, int out_size, void* d_ws, size_t ws_size,
                              hipStream_t stream) {
  const float* inp = (const float*)d_in[0];
  const float* W   = (const float*)d_in[1];
  // defensive: inputs is 1M elems, W is 33.5M elems
  if (n_in >= 2 && in_sizes[0] > in_sizes[1]) { const float* tmp = inp; inp = W; W = tmp; }
  float* out = (float*)d_out;
  char* ws = (char*)d_ws;
  (void)out_size;

  // proven layout: Xt@0 (2MB) | part (nch*128KB) | vsum (128KB) | part2 (RG*128KB)
  int nch = 256;
  while (nch > 32 &&
         (size_t)(2u << 20) + (size_t)nch * 131072u + 131072u +
             (size_t)(nch / 32) * 131072u > ws_size)
    nch >>= 1;
  const int ipb = NI / nch;
  const int RG = nch / 32;

  unsigned short* Xt = (unsigned short*)ws;
  float* part  = (float*)(ws + (2u << 20));
  float* vsum  = part + (size_t)NJ * nch * NB * ND;   // full part extent
  float* part2 = vsum + (size_t)NB * NJ * ND;         // after vsum

  kern_prep<<<1024, 256, 0, stream>>>(inp, Xt);

  // iter 0: uniform c = 1/32
  kern_fused<true><<<nch, 1024, 0, stream>>>(W, Xt, nullptr, part, ipb, nch);
  kern_reduce1<<<32 * RG, 1024, 0, stream>>>(part, part2, nch, RG);
  kern_squash<<<32, 1024, 0, stream>>>(part2, vsum, out, 0, RG);

  // iter 1
  kern_fused<false><<<nch, 1024, 0, stream>>>(W, Xt, vsum, part, ipb, nch);
  kern_reduce1<<<32 * RG, 1024, 0, stream>>>(part, part2, nch, RG);
  kern_squash<<<32, 1024, 0, stream>>>(part2, vsum, out, 1, RG);

  // iter 2
  kern_fused<false><<<nch, 1024, 0, stream>>>(W, Xt, vsum, part, ipb, nch);
  kern_reduce1<<<32 * RG, 1024, 0, stream>>>(part, part2, nch, RG);
  kern_squash<<<32, 1024, 0, stream>>>(part2, vsum, out, 2, RG);
}

// Round 9
// 235.990 us; speedup vs baseline: 1.0002x; 1.0002x over previous
//
#include <hip/hip_runtime.h>

#define NB 32
#define NI 2048
#define NP 16
#define NJ 32
#define ND 32
#define EPSF 1e-7f

typedef __attribute__((ext_vector_type(8))) short bf16x8;
typedef __attribute__((ext_vector_type(16))) float f32x16;
typedef __attribute__((ext_vector_type(4))) float f32x4;

static __device__ __forceinline__ unsigned cvt_pk_bf16(float lo, float hi) {
  unsigned r;
  asm("v_cvt_pk_bf16_f32 %0, %1, %2" : "=v"(r) : "v"(lo), "v"(hi));
  return r;
}

static __device__ __forceinline__ f32x16 mfma_bf16(bf16x8 a, bf16x8 b, f32x16 c) {
  return __builtin_amdgcn_mfma_f32_32x32x16_bf16(a, b, c, 0, 0, 0);
}

// A operand for U^T = W^T(d x p) @ X^T(p x b), one (i,j), from raw f32 W.
// lane l: m = d = l&31, k = p = 8*(l>>5) + e  (e = 0..7)
static __device__ __forceinline__ bf16x8 load_wfrag_f32(const float* __restrict__ W,
                                                        int i, int j, int h, int d) {
  const float* wp = W + (((size_t)i * NJ + j) * NP + h * 8) * ND + d;
  union { unsigned u[4]; bf16x8 v; } wf;
  wf.u[0] = cvt_pk_bf16(wp[0 * ND], wp[1 * ND]);
  wf.u[1] = cvt_pk_bf16(wp[2 * ND], wp[3 * ND]);
  wf.u[2] = cvt_pk_bf16(wp[4 * ND], wp[5 * ND]);
  wf.u[3] = cvt_pk_bf16(wp[6 * ND], wp[7 * ND]);
  return wf.v;
}

// B operand: lane l: k = p = 8*(l>>5)+e, n = b = l&31
static __device__ __forceinline__ bf16x8 load_xfrag(const unsigned short* __restrict__ Xt,
                                                    int i, int b, int h) {
  return *(const bf16x8*)(Xt + ((size_t)i * NB + b) * NP + h * 8);
}

// ---------- prep: inputs[b][i][p] (f32) -> Xt[i][b][p] (bf16) ----------
__global__ __launch_bounds__(256) void kern_prep(const float* __restrict__ in,
                                                 unsigned short* __restrict__ Xt) {
  const int t = blockIdx.x * 256 + threadIdx.x;   // 262144 threads, 4 elems each
  const int rest = t >> 2;                        // b*NI + i
  const int p4 = (t & 3) * 4;
  const int i = rest & (NI - 1);
  const int b = rest >> 11;
  f32x4 x = *(const f32x4*)(in + (size_t)rest * NP + p4);
  uint2 v;
  v.x = cvt_pk_bf16(x[0], x[1]);
  v.y = cvt_pk_bf16(x[2], x[3]);
  *(uint2*)(Xt + ((size_t)i * NB + b) * NP + p4) = v;
}

// ---------- fused: [logits -> softmax ->] weighted partial sum over i-chunk ----
// 1024 threads = 16 waves; wave w owns j = w*2 + t (t=0..1).
// __launch_bounds__(1024, 4): min 4 waves/EU -> VGPR cap 128. R8's bare (1024)
// made hipcc target 64 VGPR and SPILL (VGPR_Count=64, WRITE_SIZE 69MB vs 32MB
// legit) -> 91us/pass. Live state ~90 regs fits 128 with zero spills.
// block ch handles i in [ch*ipb, ch*ipb+ipb). part[j][ch][b][d] partials.
// UNIFORM: c = 1/32 (routing iter 0), no logits/softmax needed.
template <bool UNIFORM>
__global__ __launch_bounds__(1024, 4) void kern_fused(const float* __restrict__ W,
                                                      const unsigned short* __restrict__ Xt,
                                                      const float* __restrict__ vsum,
                                                      float* __restrict__ part,
                                                      int ipb, int nch) {
  const int tid = threadIdx.x;
  const int w = tid >> 6;        // 0..15
  const int lane = tid & 63;
  const int b = lane & 31;
  const int h = lane >> 5;
  const int ch = blockIdx.x;

  // register-resident vsum fragment: vs[t][q][e] = vsum[b][j=w*2+t][8q + 4h + e]
  f32x4 vs[2][4];
  if (!UNIFORM) {
#pragma unroll
    for (int t = 0; t < 2; ++t) {
      const int j = w * 2 + t;
#pragma unroll
      for (int q = 0; q < 4; ++q)
        vs[t][q] = *(const f32x4*)(vsum + ((size_t)b * NJ + j) * ND + q * 8 + h * 4);
    }
  }

  f32x16 sacc[2] = {};
  __shared__ float lgt[NJ][33];   // single buffer, 2 barriers per ii (proven structure)

  for (int ii = 0; ii < ipb; ++ii) {
    const int i = ch * ipb + ii;
    const bf16x8 xf = load_xfrag(Xt, i, b, h);
    if (UNIFORM) {
#pragma unroll
      for (int t = 0; t < 2; ++t)
        sacc[t] = mfma_bf16(load_wfrag_f32(W, i, w * 2 + t, h, b), xf, sacc[t]);
    } else {
      f32x16 um[2];
      float lg[2];
#pragma unroll
      for (int t = 0; t < 2; ++t) {
        const int j = w * 2 + t;
        f32x16 z = {};
        um[t] = mfma_bf16(load_wfrag_f32(W, i, j, h, b), xf, z);  // um[r]=U^T[d(r)][b]
        float p = 0.f;
#pragma unroll
        for (int r = 0; r < 16; ++r)
          p += um[t][r] * vs[t][r >> 2][r & 3];   // d(r) = (r&3) + 8*(r>>2) + 4h
        p += __shfl_xor(p, 32);                   // add partner half's 16 d's
        lg[t] = p;
      }
      if (h == 0) {
#pragma unroll
        for (int t = 0; t < 2; ++t) lgt[w * 2 + t][b] = lg[t];
      }
      __syncthreads();
      // per-(b,i) softmax over j (each thread reduces its own b's column)
      float mx = -3.0e38f;
#pragma unroll
      for (int jj = 0; jj < NJ; ++jj) mx = fmaxf(mx, lgt[jj][b]);
      float den = 0.f;
#pragma unroll
      for (int jj = 0; jj < NJ; ++jj) den += expf(lgt[jj][b] - mx);
      const float inv = 1.0f / den;
#pragma unroll
      for (int t = 0; t < 2; ++t) {
        const float c = expf(lg[t] - mx) * inv;
#pragma unroll
        for (int r = 0; r < 16; ++r) sacc[t][r] += c * um[t][r];
      }
      __syncthreads();   // protect lgt before next i overwrites it
    }
  }

#pragma unroll
  for (int t = 0; t < 2; ++t) {
    const int j = w * 2 + t;
#pragma unroll
    for (int r = 0; r < 16; ++r) {
      const float val = UNIFORM ? sacc[t][r] * (1.0f / 32.0f) : sacc[t][r];
      const int d = (r & 3) + 8 * (r >> 2) + 4 * h;
      part[(((size_t)j * nch + ch) * NB + b) * ND + d] = val;
    }
  }
}

// ---------- stage-1 reduce: 32-chunk groups -> part2[j][r][b][d] ----------
__global__ __launch_bounds__(1024) void kern_reduce1(const float* __restrict__ part,
                                                     float* __restrict__ part2,
                                                     int nch, int RG) {
  const int j = blockIdx.x / RG;
  const int r = blockIdx.x % RG;
  const int t = threadIdx.x;
  const int b = t >> 5;
  const int d = t & 31;
  float s = 0.f;
#pragma unroll 4
  for (int c = 0; c < 32; ++c)
    s += part[(((size_t)j * nch + r * 32 + c) * NB + b) * ND + d];
  part2[(((size_t)j * RG + r) * NB + b) * ND + d] = s;
}

// ---------- final reduce + squash + vsum/out ----------
__global__ __launch_bounds__(1024) void kern_squash(const float* __restrict__ part2,
                                                    float* __restrict__ vsum,
                                                    float* __restrict__ out,
                                                    int mode, int RG) {
  const int j = blockIdx.x;
  const int t = threadIdx.x;
  const int b = t >> 5;
  const int d = t & 31;
  float s = 0.f;
  for (int r = 0; r < RG; ++r)
    s += part2[(((size_t)j * RG + r) * NB + b) * ND + d];

  __shared__ float sl[32][33];
  __shared__ float fb[32];
  sl[b][d] = s;
  __syncthreads();
  if (t < 32) {
    float n2 = 0.f;
#pragma unroll
    for (int dd = 0; dd < ND; ++dd) { const float x = sl[t][dd]; n2 += x * x; }
    fb[t] = n2 / ((1.0f + n2) * sqrtf(n2 + EPSF));
  }
  __syncthreads();
  const float v = s * fb[b];
  const int idx = (b * NJ + j) * ND + d;
  if (mode == 0)      vsum[idx] = v;        // iter0: vsum := v0 (never read-before-write)
  else if (mode == 1) vsum[idx] += v;       // iter1: vsum := v0+v1
  else                out[idx] = v;         // iter2: final output [B,J,D]
}

extern "C" void kernel_launch(void* const* d_in, const int* in_sizes, int n_in,
                              void* d_out, int out_size, void* d_ws, size_t ws_size,
                              hipStream_t stream) {
  const float* inp = (const float*)d_in[0];
  const float* W   = (const float*)d_in[1];
  // defensive: inputs is 1M elems, W is 33.5M elems
  if (n_in >= 2 && in_sizes[0] > in_sizes[1]) { const float* tmp = inp; inp = W; W = tmp; }
  float* out = (float*)d_out;
  char* ws = (char*)d_ws;
  (void)out_size;

  // proven layout: Xt@0 (2MB) | part (nch*128KB) | vsum (128KB) | part2 (RG*128KB)
  int nch = 256;
  while (nch > 32 &&
         (size_t)(2u << 20) + (size_t)nch * 131072u + 131072u +
             (size_t)(nch / 32) * 131072u > ws_size)
    nch >>= 1;
  const int ipb = NI / nch;
  const int RG = nch / 32;

  unsigned short* Xt = (unsigned short*)ws;
  float* part  = (float*)(ws + (2u << 20));
  float* vsum  = part + (size_t)NJ * nch * NB * ND;   // full part extent
  float* part2 = vsum + (size_t)NB * NJ * ND;         // after vsum

  kern_prep<<<1024, 256, 0, stream>>>(inp, Xt);

  // iter 0: uniform c = 1/32
  kern_fused<true><<<nch, 1024, 0, stream>>>(W, Xt, nullptr, part, ipb, nch);
  kern_reduce1<<<32 * RG, 1024, 0, stream>>>(part, part2, nch, RG);
  kern_squash<<<32, 1024, 0, stream>>>(part2, vsum, out, 0, RG);

  // iter 1
  kern_fused<false><<<nch, 1024, 0, stream>>>(W, Xt, vsum, part, ipb, nch);
  kern_reduce1<<<32 * RG, 1024, 0, stream>>>(part, part2, nch, RG);
  kern_squash<<<32, 1024, 0, stream>>>(part2, vsum, out, 1, RG);

  // iter 2
  kern_fused<false><<<nch, 1024, 0, stream>>>(W, Xt, vsum, part, ipb, nch);
  kern_reduce1<<<32 * RG, 1024, 0, stream>>>(part, part2, nch, RG);
  kern_squash<<<32, 1024, 0, stream>>>(part2, vsum, out, 2, RG);
}

// Round 10
// 235.985 us; speedup vs baseline: 1.0003x; 1.0000x over previous
//
#include <hip/hip_runtime.h>

#define NB 32
#define NI 2048
#define NP 16
#define NJ 32
#define ND 32
#define EPSF 1e-7f

typedef __attribute__((ext_vector_type(8))) short bf16x8;
typedef __attribute__((ext_vector_type(16))) float f32x16;
typedef __attribute__((ext_vector_type(4))) float f32x4;

static __device__ __forceinline__ unsigned cvt_pk_bf16(float lo, float hi) {
  unsigned r;
  asm("v_cvt_pk_bf16_f32 %0, %1, %2" : "=v"(r) : "v"(lo), "v"(hi));
  return r;
}

static __device__ __forceinline__ f32x16 mfma_bf16(bf16x8 a, bf16x8 b, f32x16 c) {
  return __builtin_amdgcn_mfma_f32_32x32x16_bf16(a, b, c, 0, 0, 0);
}

// A operand for U^T = W^T(d x p) @ X^T(p x b), one (i,j), from raw f32 W.
// lane l: m = d = l&31, k = p = 8*(l>>5) + e  (e = 0..7)
static __device__ __forceinline__ bf16x8 load_wfrag_f32(const float* __restrict__ W,
                                                        int i, int j, int h, int d) {
  const float* wp = W + (((size_t)i * NJ + j) * NP + h * 8) * ND + d;
  union { unsigned u[4]; bf16x8 v; } wf;
  wf.u[0] = cvt_pk_bf16(wp[0 * ND], wp[1 * ND]);
  wf.u[1] = cvt_pk_bf16(wp[2 * ND], wp[3 * ND]);
  wf.u[2] = cvt_pk_bf16(wp[4 * ND], wp[5 * ND]);
  wf.u[3] = cvt_pk_bf16(wp[6 * ND], wp[7 * ND]);
  return wf.v;
}

// B operand: lane l: k = p = 8*(l>>5)+e, n = b = l&31
static __device__ __forceinline__ bf16x8 load_xfrag(const unsigned short* __restrict__ Xt,
                                                    int i, int b, int h) {
  return *(const bf16x8*)(Xt + ((size_t)i * NB + b) * NP + h * 8);
}

// ---------- prep: inputs[b][i][p] (f32) -> Xt[i][b][p] (bf16) ----------
__global__ __launch_bounds__(256) void kern_prep(const float* __restrict__ in,
                                                 unsigned short* __restrict__ Xt) {
  const int t = blockIdx.x * 256 + threadIdx.x;   // 262144 threads, 4 elems each
  const int rest = t >> 2;                        // b*NI + i
  const int p4 = (t & 3) * 4;
  const int i = rest & (NI - 1);
  const int b = rest >> 11;
  f32x4 x = *(const f32x4*)(in + (size_t)rest * NP + p4);
  uint2 v;
  v.x = cvt_pk_bf16(x[0], x[1]);
  v.y = cvt_pk_bf16(x[2], x[3]);
  *(uint2*)(Xt + ((size_t)i * NB + b) * NP + p4) = v;
}

// ---------- fused: [logits -> softmax ->] weighted partial sum over i-chunk ----
// 1024 threads = 16 waves; wave w owns j = w*2 + t (t=0..1).
// __launch_bounds__(1024, 2): VGPR cap 256. History: bare (1024) and (1024,4)
// both made hipcc allocate 64 VGPR and SPILL (WRITE_SIZE 69MB vs 32MB legit,
// 91us/pass). Grid is 1 block/CU, so occupancy = this block's own 16 waves;
// the 2nd arg only needs to stop the compiler optimizing for a 2nd block.
// block ch handles i in [ch*ipb, ch*ipb+ipb). part[j][ch][b][d] partials.
// UNIFORM: c = 1/32 (routing iter 0), no logits/softmax needed.
template <bool UNIFORM>
__global__ __launch_bounds__(1024, 2) void kern_fused(const float* __restrict__ W,
                                                      const unsigned short* __restrict__ Xt,
                                                      const float* __restrict__ vsum,
                                                      float* __restrict__ part,
                                                      int ipb, int nch) {
  const int tid = threadIdx.x;
  const int w = tid >> 6;        // 0..15
  const int lane = tid & 63;
  const int b = lane & 31;
  const int h = lane >> 5;
  const int ch = blockIdx.x;

  // register-resident vsum fragment: vs[t][q][e] = vsum[b][j=w*2+t][8q + 4h + e]
  f32x4 vs[2][4];
  if (!UNIFORM) {
#pragma unroll
    for (int t = 0; t < 2; ++t) {
      const int j = w * 2 + t;
#pragma unroll
      for (int q = 0; q < 4; ++q)
        vs[t][q] = *(const f32x4*)(vsum + ((size_t)b * NJ + j) * ND + q * 8 + h * 4);
    }
  }

  f32x16 sacc[2] = {};
  __shared__ float lgt[NJ][33];   // single buffer, 2 barriers per ii (proven structure)

  for (int ii = 0; ii < ipb; ++ii) {
    const int i = ch * ipb + ii;
    const bf16x8 xf = load_xfrag(Xt, i, b, h);
    if (UNIFORM) {
#pragma unroll
      for (int t = 0; t < 2; ++t)
        sacc[t] = mfma_bf16(load_wfrag_f32(W, i, w * 2 + t, h, b), xf, sacc[t]);
    } else {
      f32x16 um[2];
      float lg[2];
#pragma unroll
      for (int t = 0; t < 2; ++t) {
        const int j = w * 2 + t;
        f32x16 z = {};
        um[t] = mfma_bf16(load_wfrag_f32(W, i, j, h, b), xf, z);  // um[r]=U^T[d(r)][b]
        float p = 0.f;
#pragma unroll
        for (int r = 0; r < 16; ++r)
          p += um[t][r] * vs[t][r >> 2][r & 3];   // d(r) = (r&3) + 8*(r>>2) + 4h
        p += __shfl_xor(p, 32);                   // add partner half's 16 d's
        lg[t] = p;
      }
      if (h == 0) {
#pragma unroll
        for (int t = 0; t < 2; ++t) lgt[w * 2 + t][b] = lg[t];
      }
      __syncthreads();
      // per-(b,i) softmax over j (each thread reduces its own b's column)
      float mx = -3.0e38f;
#pragma unroll
      for (int jj = 0; jj < NJ; ++jj) mx = fmaxf(mx, lgt[jj][b]);
      float den = 0.f;
#pragma unroll
      for (int jj = 0; jj < NJ; ++jj) den += expf(lgt[jj][b] - mx);
      const float inv = 1.0f / den;
#pragma unroll
      for (int t = 0; t < 2; ++t) {
        const float c = expf(lg[t] - mx) * inv;
#pragma unroll
        for (int r = 0; r < 16; ++r) sacc[t][r] += c * um[t][r];
      }
      __syncthreads();   // protect lgt before next i overwrites it
    }
  }

#pragma unroll
  for (int t = 0; t < 2; ++t) {
    const int j = w * 2 + t;
#pragma unroll
    for (int r = 0; r < 16; ++r) {
      const float val = UNIFORM ? sacc[t][r] * (1.0f / 32.0f) : sacc[t][r];
      const int d = (r & 3) + 8 * (r >> 2) + 4 * h;
      part[(((size_t)j * nch + ch) * NB + b) * ND + d] = val;
    }
  }
}

// ---------- stage-1 reduce: 32-chunk groups -> part2[j][r][b][d] ----------
__global__ __launch_bounds__(1024) void kern_reduce1(const float* __restrict__ part,
                                                     float* __restrict__ part2,
                                                     int nch, int RG) {
  const int j = blockIdx.x / RG;
  const int r = blockIdx.x % RG;
  const int t = threadIdx.x;
  const int b = t >> 5;
  const int d = t & 31;
  float s = 0.f;
#pragma unroll 4
  for (int c = 0; c < 32; ++c)
    s += part[(((size_t)j * nch + r * 32 + c) * NB + b) * ND + d];
  part2[(((size_t)j * RG + r) * NB + b) * ND + d] = s;
}

// ---------- final reduce + squash + vsum/out ----------
__global__ __launch_bounds__(1024) void kern_squash(const float* __restrict__ part2,
                                                    float* __restrict__ vsum,
                                                    float* __restrict__ out,
                                                    int mode, int RG) {
  const int j = blockIdx.x;
  const int t = threadIdx.x;
  const int b = t >> 5;
  const int d = t & 31;
  float s = 0.f;
  for (int r = 0; r < RG; ++r)
    s += part2[(((size_t)j * RG + r) * NB + b) * ND + d];

  __shared__ float sl[32][33];
  __shared__ float fb[32];
  sl[b][d] = s;
  __syncthreads();
  if (t < 32) {
    float n2 = 0.f;
#pragma unroll
    for (int dd = 0; dd < ND; ++dd) { const float x = sl[t][dd]; n2 += x * x; }
    fb[t] = n2 / ((1.0f + n2) * sqrtf(n2 + EPSF));
  }
  __syncthreads();
  const float v = s * fb[b];
  const int idx = (b * NJ + j) * ND + d;
  if (mode == 0)      vsum[idx] = v;        // iter0: vsum := v0 (never read-before-write)
  else if (mode == 1) vsum[idx] += v;       // iter1: vsum := v0+v1
  else                out[idx] = v;         // iter2: final output [B,J,D]
}

extern "C" void kernel_launch(void* const* d_in, const int* in_sizes, int n_in,
                              void* d_out, int out_size, void* d_ws, size_t ws_size,
                              hipStream_t stream) {
  const float* inp = (const float*)d_in[0];
  const float* W   = (const float*)d_in[1];
  // defensive: inputs is 1M elems, W is 33.5M elems
  if (n_in >= 2 && in_sizes[0] > in_sizes[1]) { const float* tmp = inp; inp = W; W = tmp; }
  float* out = (float*)d_out;
  char* ws = (char*)d_ws;
  (void)out_size;

  // proven layout: Xt@0 (2MB) | part (nch*128KB) | vsum (128KB) | part2 (RG*128KB)
  int nch = 256;
  while (nch > 32 &&
         (size_t)(2u << 20) + (size_t)nch * 131072u + 131072u +
             (size_t)(nch / 32) * 131072u > ws_size)
    nch >>= 1;
  const int ipb = NI / nch;
  const int RG = nch / 32;

  unsigned short* Xt = (unsigned short*)ws;
  float* part  = (float*)(ws + (2u << 20));
  float* vsum  = part + (size_t)NJ * nch * NB * ND;   // full part extent
  float* part2 = vsum + (size_t)NB * NJ * ND;         // after vsum

  kern_prep<<<1024, 256, 0, stream>>>(inp, Xt);

  // iter 0: uniform c = 1/32
  kern_fused<true><<<nch, 1024, 0, stream>>>(W, Xt, nullptr, part, ipb, nch);
  kern_reduce1<<<32 * RG, 1024, 0, stream>>>(part, part2, nch, RG);
  kern_squash<<<32, 1024, 0, stream>>>(part2, vsum, out, 0, RG);

  // iter 1
  kern_fused<false><<<nch, 1024, 0, stream>>>(W, Xt, vsum, part, ipb, nch);
  kern_reduce1<<<32 * RG, 1024, 0, stream>>>(part, part2, nch, RG);
  kern_squash<<<32, 1024, 0, stream>>>(part2, vsum, out, 1, RG);

  // iter 2
  kern_fused<false><<<nch, 1024, 0, stream>>>(W, Xt, vsum, part, ipb, nch);
  kern_reduce1<<<32 * RG, 1024, 0, stream>>>(part, part2, nch, RG);
  kern_squash<<<32, 1024, 0, stream>>>(part2, vsum, out, 2, RG);
}

// Round 11
// 195.988 us; speedup vs baseline: 1.2044x; 1.2041x over previous
//
#include <hip/hip_runtime.h>

#define NB 32
#define NI 2048
#define NP 16
#define NJ 32
#define ND 32
#define EPSF 1e-7f

typedef __attribute__((ext_vector_type(8))) short bf16x8;
typedef __attribute__((ext_vector_type(16))) float f32x16;
typedef __attribute__((ext_vector_type(4))) float f32x4;

static __device__ __forceinline__ unsigned cvt_pk_bf16(float lo, float hi) {
  unsigned r;
  asm("v_cvt_pk_bf16_f32 %0, %1, %2" : "=v"(r) : "v"(lo), "v"(hi));
  return r;
}

static __device__ __forceinline__ f32x16 mfma_bf16(bf16x8 a, bf16x8 b, f32x16 c) {
  return __builtin_amdgcn_mfma_f32_32x32x16_bf16(a, b, c, 0, 0, 0);
}

// non-temporal helpers: keep the streaming `part` traffic from evicting W
// (128 MiB, fits 256 MiB L3) between routing passes.
static __device__ __forceinline__ void nt_store(float v, float* p) {
  __builtin_nontemporal_store(v, p);
}
static __device__ __forceinline__ float nt_load(const float* p) {
  return __builtin_nontemporal_load(p);
}

// A operand for U^T = W^T(d x p) @ X^T(p x b), one (i,j), from raw f32 W.
// lane l: m = d = l&31, k = p = 8*(l>>5) + e  (e = 0..7)
static __device__ __forceinline__ bf16x8 load_wfrag_f32(const float* __restrict__ W,
                                                        int i, int j, int h, int d) {
  const float* wp = W + (((size_t)i * NJ + j) * NP + h * 8) * ND + d;
  union { unsigned u[4]; bf16x8 v; } wf;
  wf.u[0] = cvt_pk_bf16(wp[0 * ND], wp[1 * ND]);
  wf.u[1] = cvt_pk_bf16(wp[2 * ND], wp[3 * ND]);
  wf.u[2] = cvt_pk_bf16(wp[4 * ND], wp[5 * ND]);
  wf.u[3] = cvt_pk_bf16(wp[6 * ND], wp[7 * ND]);
  return wf.v;
}

// B operand: lane l: k = p = 8*(l>>5)+e, n = b = l&31
static __device__ __forceinline__ bf16x8 load_xfrag(const unsigned short* __restrict__ Xt,
                                                    int i, int b, int h) {
  return *(const bf16x8*)(Xt + ((size_t)i * NB + b) * NP + h * 8);
}

// ---------- prep: inputs[b][i][p] (f32) -> Xt[i][b][p] (bf16) ----------
__global__ __launch_bounds__(256) void kern_prep(const float* __restrict__ in,
                                                 unsigned short* __restrict__ Xt) {
  const int t = blockIdx.x * 256 + threadIdx.x;   // 262144 threads, 4 elems each
  const int rest = t >> 2;                        // b*NI + i
  const int p4 = (t & 3) * 4;
  const int i = rest & (NI - 1);
  const int b = rest >> 11;
  f32x4 x = *(const f32x4*)(in + (size_t)rest * NP + p4);
  uint2 v;
  v.x = cvt_pk_bf16(x[0], x[1]);
  v.y = cvt_pk_bf16(x[2], x[3]);
  *(uint2*)(Xt + ((size_t)i * NB + b) * NP + p4) = v;
}

// ---------- fused: [logits -> softmax ->] weighted partial sum over i-chunk ----
// 512 threads = 8 waves; wave w owns j = w*4 + t (t=0..3).  (proven R5 shape:
// 1024-thread variants force a 64-VGPR budget and spill -> 91us/pass.)
// block ch handles i in [ch*ipb, ch*ipb+ipb). part[j][ch][b][d] partials (NT).
// UNIFORM: c = 1/32 (routing iter 0), no logits/softmax needed.
template <bool UNIFORM>
__global__ __launch_bounds__(512) void kern_fused(const float* __restrict__ W,
                                                  const unsigned short* __restrict__ Xt,
                                                  const float* __restrict__ vsum,
                                                  float* __restrict__ part,
                                                  int ipb, int nch) {
  const int tid = threadIdx.x;
  const int w = tid >> 6;
  const int lane = tid & 63;
  const int b = lane & 31;
  const int h = lane >> 5;
  const int ch = blockIdx.x;

  // register-resident vsum fragment: vs[t][q][e] = vsum[b][j=w*4+t][8q + 4h + e]
  f32x4 vs[4][4];
  if (!UNIFORM) {
#pragma unroll
    for (int t = 0; t < 4; ++t) {
      const int j = w * 4 + t;
#pragma unroll
      for (int q = 0; q < 4; ++q)
        vs[t][q] = *(const f32x4*)(vsum + ((size_t)b * NJ + j) * ND + q * 8 + h * 4);
    }
  }

  f32x16 sacc[4] = {};
  __shared__ float lgt[NJ][33];

  for (int ii = 0; ii < ipb; ++ii) {
    const int i = ch * ipb + ii;
    const bf16x8 xf = load_xfrag(Xt, i, b, h);
    if (UNIFORM) {
#pragma unroll
      for (int t = 0; t < 4; ++t)
        sacc[t] = mfma_bf16(load_wfrag_f32(W, i, w * 4 + t, h, b), xf, sacc[t]);
    } else {
      f32x16 um[4];
      float lg[4];
#pragma unroll
      for (int t = 0; t < 4; ++t) {
        const int j = w * 4 + t;
        f32x16 z = {};
        um[t] = mfma_bf16(load_wfrag_f32(W, i, j, h, b), xf, z);  // um[r]=U^T[d(r)][b]
        float p = 0.f;
#pragma unroll
        for (int r = 0; r < 16; ++r)
          p += um[t][r] * vs[t][r >> 2][r & 3];   // d(r) = (r&3) + 8*(r>>2) + 4h
        p += __shfl_xor(p, 32);                   // add partner half's 16 d's
        lg[t] = p;
      }
      if (h == 0) {
#pragma unroll
        for (int t = 0; t < 4; ++t) lgt[w * 4 + t][b] = lg[t];
      }
      __syncthreads();
      // per-(b,i) softmax over j (each thread reduces its own b's column)
      float mx = -3.0e38f;
#pragma unroll
      for (int jj = 0; jj < NJ; ++jj) mx = fmaxf(mx, lgt[jj][b]);
      float den = 0.f;
#pragma unroll
      for (int jj = 0; jj < NJ; ++jj) den += expf(lgt[jj][b] - mx);
      const float inv = 1.0f / den;
#pragma unroll
      for (int t = 0; t < 4; ++t) {
        const float c = expf(lg[t] - mx) * inv;
#pragma unroll
        for (int r = 0; r < 16; ++r) sacc[t][r] += c * um[t][r];
      }
      __syncthreads();   // protect lgt before next i overwrites it
    }
  }

#pragma unroll
  for (int t = 0; t < 4; ++t) {
    const int j = w * 4 + t;
#pragma unroll
    for (int r = 0; r < 16; ++r) {
      const float val = UNIFORM ? sacc[t][r] * (1.0f / 32.0f) : sacc[t][r];
      const int d = (r & 3) + 8 * (r >> 2) + 4 * h;
      nt_store(val, &part[(((size_t)j * nch + ch) * NB + b) * ND + d]);
    }
  }
}

// ---------- stage-1 reduce: 32-chunk groups -> part2[j][r][b][d] ----------
// grid: 32*RG blocks, 1024 threads (t = b*32 + d). NT on the 32MB part stream.
__global__ __launch_bounds__(1024) void kern_reduce1(const float* __restrict__ part,
                                                     float* __restrict__ part2,
                                                     int nch, int RG) {
  const int j = blockIdx.x / RG;
  const int r = blockIdx.x % RG;
  const int t = threadIdx.x;
  const int b = t >> 5;
  const int d = t & 31;
  float s = 0.f;
#pragma unroll 4
  for (int c = 0; c < 32; ++c)
    s += nt_load(&part[(((size_t)j * nch + r * 32 + c) * NB + b) * ND + d]);
  nt_store(s, &part2[(((size_t)j * RG + r) * NB + b) * ND + d]);
}

// ---------- final reduce + squash + vsum/out ----------
// grid: 32 blocks (one j), 1024 threads: t = b*32 + d.
__global__ __launch_bounds__(1024) void kern_squash(const float* __restrict__ part2,
                                                    float* __restrict__ vsum,
                                                    float* __restrict__ out,
                                                    int mode, int RG) {
  const int j = blockIdx.x;
  const int t = threadIdx.x;
  const int b = t >> 5;
  const int d = t & 31;
  float s = 0.f;
  for (int r = 0; r < RG; ++r)
    s += nt_load(&part2[(((size_t)j * RG + r) * NB + b) * ND + d]);

  __shared__ float sl[32][33];
  __shared__ float fb[32];
  sl[b][d] = s;
  __syncthreads();
  if (t < 32) {
    float n2 = 0.f;
#pragma unroll
    for (int dd = 0; dd < ND; ++dd) { const float x = sl[t][dd]; n2 += x * x; }
    fb[t] = n2 / ((1.0f + n2) * sqrtf(n2 + EPSF));
  }
  __syncthreads();
  const float v = s * fb[b];
  const int idx = (b * NJ + j) * ND + d;
  if (mode == 0)      vsum[idx] = v;        // iter0: vsum := v0 (never read-before-write)
  else if (mode == 1) vsum[idx] += v;       // iter1: vsum := v0+v1
  else                out[idx] = v;         // iter2: final output [B,J,D]
}

extern "C" void kernel_launch(void* const* d_in, const int* in_sizes, int n_in,
                              void* d_out, int out_size, void* d_ws, size_t ws_size,
                              hipStream_t stream) {
  const float* inp = (const float*)d_in[0];
  const float* W   = (const float*)d_in[1];
  // defensive: inputs is 1M elems, W is 33.5M elems
  if (n_in >= 2 && in_sizes[0] > in_sizes[1]) { const float* tmp = inp; inp = W; W = tmp; }
  float* out = (float*)d_out;
  char* ws = (char*)d_ws;
  (void)out_size;

  // proven layout: Xt@0 (2MB) | part (nch*128KB) | vsum (128KB) | part2 (RG*128KB)
  int nch = 256;
  while (nch > 32 &&
         (size_t)(2u << 20) + (size_t)nch * 131072u + 131072u +
             (size_t)(nch / 32) * 131072u > ws_size)
    nch >>= 1;
  const int ipb = NI / nch;
  const int RG = nch / 32;

  unsigned short* Xt = (unsigned short*)ws;
  float* part  = (float*)(ws + (2u << 20));
  float* vsum  = part + (size_t)NJ * nch * NB * ND;   // full part extent
  float* part2 = vsum + (size_t)NB * NJ * ND;         // after vsum

  kern_prep<<<1024, 256, 0, stream>>>(inp, Xt);

  // iter 0: uniform c = 1/32
  kern_fused<true><<<nch, 512, 0, stream>>>(W, Xt, nullptr, part, ipb, nch);
  kern_reduce1<<<32 * RG, 1024, 0, stream>>>(part, part2, nch, RG);
  kern_squash<<<32, 1024, 0, stream>>>(part2, vsum, out, 0, RG);

  // iter 1
  kern_fused<false><<<nch, 512, 0, stream>>>(W, Xt, vsum, part, ipb, nch);
  kern_reduce1<<<32 * RG, 1024, 0, stream>>>(part, part2, nch, RG);
  kern_squash<<<32, 1024, 0, stream>>>(part2, vsum, out, 1, RG);

  // iter 2
  kern_fused<false><<<nch, 512, 0, stream>>>(W, Xt, vsum, part, ipb, nch);
  kern_reduce1<<<32 * RG, 1024, 0, stream>>>(part, part2, nch, RG);
  kern_squash<<<32, 1024, 0, stream>>>(part2, vsum, out, 2, RG);
}

// Round 12
// 162.206 us; speedup vs baseline: 1.4552x; 1.2083x over previous
//
#include <hip/hip_runtime.h>

#define NB 32
#define NI 2048
#define NP 16
#define NJ 32
#define ND 32
#define EPSF 1e-7f

typedef __attribute__((ext_vector_type(8))) short bf16x8;
typedef __attribute__((ext_vector_type(16))) float f32x16;
typedef __attribute__((ext_vector_type(4))) float f32x4;

static __device__ __forceinline__ unsigned cvt_pk_bf16(float lo, float hi) {
  unsigned r;
  asm("v_cvt_pk_bf16_f32 %0, %1, %2" : "=v"(r) : "v"(lo), "v"(hi));
  return r;
}

static __device__ __forceinline__ f32x16 mfma_bf16(bf16x8 a, bf16x8 b, f32x16 c) {
  return __builtin_amdgcn_mfma_f32_32x32x16_bf16(a, b, c, 0, 0, 0);
}

static __device__ __forceinline__ float nt_load(const float* p) {
  return __builtin_nontemporal_load(p);   // read + LRU-evict hint (dead-after-read only)
}

// A operand for U^T = W^T(d x p) @ X^T(p x b), one (i,j), from raw f32 W.
// lane l: m = d = l&31, k = p = 8*(l>>5) + e  (e = 0..7)
static __device__ __forceinline__ bf16x8 load_wfrag_f32(const float* __restrict__ W,
                                                        int i, int j, int h, int d) {
  const float* wp = W + (((size_t)i * NJ + j) * NP + h * 8) * ND + d;
  union { unsigned u[4]; bf16x8 v; } wf;
  wf.u[0] = cvt_pk_bf16(wp[0 * ND], wp[1 * ND]);
  wf.u[1] = cvt_pk_bf16(wp[2 * ND], wp[3 * ND]);
  wf.u[2] = cvt_pk_bf16(wp[4 * ND], wp[5 * ND]);
  wf.u[3] = cvt_pk_bf16(wp[6 * ND], wp[7 * ND]);
  return wf.v;
}

// B operand: lane l: k = p = 8*(l>>5)+e, n = b = l&31
static __device__ __forceinline__ bf16x8 load_xfrag(const unsigned short* __restrict__ Xt,
                                                    int i, int b, int h) {
  return *(const bf16x8*)(Xt + ((size_t)i * NB + b) * NP + h * 8);
}

// ---------- prep: inputs[b][i][p] (f32) -> Xt[i][b][p] (bf16) ----------
__global__ __launch_bounds__(256) void kern_prep(const float* __restrict__ in,
                                                 unsigned short* __restrict__ Xt) {
  const int t = blockIdx.x * 256 + threadIdx.x;   // 262144 threads, 4 elems each
  const int rest = t >> 2;                        // b*NI + i
  const int p4 = (t & 3) * 4;
  const int i = rest & (NI - 1);
  const int b = rest >> 11;
  f32x4 x = *(const f32x4*)(in + (size_t)rest * NP + p4);
  uint2 v;
  v.x = cvt_pk_bf16(x[0], x[1]);
  v.y = cvt_pk_bf16(x[2], x[3]);
  *(uint2*)(Xt + ((size_t)i * NB + b) * NP + p4) = v;
}

// ---------- fused routing pass over an i-chunk ----------
// 512 threads = 8 waves; wave w owns j = w*4 + t (t=0..3); block ch covers ipb i's.
// SPILL FIX (R11 post-mortem: VGPR_Count=52 vs ~150 live => chronic spill):
//  - sacc is ONLY ever an MFMA C/D operand -> AGPR-resident, off the arch-VGPR
//    budget. The old `sacc += c*um` forced both sacc AND um (across the
//    barrier) into arch VGPRs.
//  - after softmax we RE-MFMA with the B operand scaled by c (c is lane-local
//    for this lane's b and wave's j): sacc = mfma(wf, bf16(x*c), sacc).
//  - amdgpu_waves_per_eu(2,2): grid is 1 block/CU (8 waves = 2/EU), so this is
//    exactly the real occupancy; raises the VGPR budget (launch_bounds' 2nd
//    arg was ignored by hipcc in R9/R10).
template <bool UNIFORM>
__global__ __attribute__((amdgpu_waves_per_eu(2, 2)))
__launch_bounds__(512) void kern_fused(const float* __restrict__ W,
                                       const unsigned short* __restrict__ Xt,
                                       const float* __restrict__ vsum,
                                       float* __restrict__ part,
                                       int ipb, int nch) {
  const int tid = threadIdx.x;
  const int w = tid >> 6;
  const int lane = tid & 63;
  const int b = lane & 31;
  const int h = lane >> 5;
  const int ch = blockIdx.x;

  // register-resident vsum fragment: vs[t][q][e] = vsum[b][j=w*4+t][8q + 4h + e]
  f32x4 vs[4][4];
  if (!UNIFORM) {
#pragma unroll
    for (int t = 0; t < 4; ++t) {
      const int j = w * 4 + t;
#pragma unroll
      for (int q = 0; q < 4; ++q)
        vs[t][q] = *(const f32x4*)(vsum + ((size_t)b * NJ + j) * ND + q * 8 + h * 4);
    }
  }

  f32x16 sacc[4] = {};
  __shared__ float lgt[NJ][33];

  for (int ii = 0; ii < ipb; ++ii) {
    const int i = ch * ipb + ii;
    const bf16x8 xf = load_xfrag(Xt, i, b, h);
    if (UNIFORM) {
#pragma unroll
      for (int t = 0; t < 4; ++t)
        sacc[t] = mfma_bf16(load_wfrag_f32(W, i, w * 4 + t, h, b), xf, sacc[t]);
    } else {
      // unpack this lane's 8 bf16 x-values to f32 once (for the c-scaled re-pack)
      union { bf16x8 v; unsigned short s[8]; } xu; xu.v = xf;
      float xf32[8];
#pragma unroll
      for (int e = 0; e < 8; ++e)
        xf32[e] = __uint_as_float((unsigned)xu.s[e] << 16);

      bf16x8 wf[4];
      float lg[4];
#pragma unroll
      for (int t = 0; t < 4; ++t) {
        wf[t] = load_wfrag_f32(W, i, w * 4 + t, h, b);
        f32x16 z = {};
        const f32x16 um = mfma_bf16(wf[t], xf, z);   // transient: dies before barrier
        float p = 0.f;
#pragma unroll
        for (int r = 0; r < 16; ++r)
          p += um[r] * vs[t][r >> 2][r & 3];         // d(r) = (r&3) + 8*(r>>2) + 4h
        p += __shfl_xor(p, 32);                      // add partner half's 16 d's
        lg[t] = p;
      }
      if (h == 0) {
#pragma unroll
        for (int t = 0; t < 4; ++t) lgt[w * 4 + t][b] = lg[t];
      }
      __syncthreads();
      // per-(b,i) softmax over j (each thread reduces its own b's column)
      float mx = -3.0e38f;
#pragma unroll
      for (int jj = 0; jj < NJ; ++jj) mx = fmaxf(mx, lgt[jj][b]);
      float den = 0.f;
#pragma unroll
      for (int jj = 0; jj < NJ; ++jj) den += expf(lgt[jj][b] - mx);
      const float inv = 1.0f / den;
#pragma unroll
      for (int t = 0; t < 4; ++t) {
        const float c = expf(lg[t] - mx) * inv;
        union { unsigned u[4]; bf16x8 v; } xc;
#pragma unroll
        for (int e = 0; e < 4; ++e)
          xc.u[e] = cvt_pk_bf16(xf32[2 * e] * c, xf32[2 * e + 1] * c);
        sacc[t] = mfma_bf16(wf[t], xc.v, sacc[t]);   // sacc stays pure-MFMA (AGPR)
      }
      __syncthreads();   // protect lgt before next i overwrites it
    }
  }

#pragma unroll
  for (int t = 0; t < 4; ++t) {
    const int j = w * 4 + t;
#pragma unroll
    for (int r = 0; r < 16; ++r) {
      const float val = UNIFORM ? sacc[t][r] * (1.0f / 32.0f) : sacc[t][r];
      const int d = (r & 3) + 8 * (r >> 2) + 4 * h;
      part[(((size_t)j * nch + ch) * NB + b) * ND + d] = val;   // normal store: cached for reduce1
    }
  }
}

// ---------- stage-1 reduce: 32-chunk groups -> part2[j][r][b][d] ----------
// nt_load: part is dead after this read -> evict-hint frees L2/L3 for W.
__global__ __launch_bounds__(1024) void kern_reduce1(const float* __restrict__ part,
                                                     float* __restrict__ part2,
                                                     int nch, int RG) {
  const int j = blockIdx.x / RG;
  const int r = blockIdx.x % RG;
  const int t = threadIdx.x;
  const int b = t >> 5;
  const int d = t & 31;
  float s = 0.f;
#pragma unroll 4
  for (int c = 0; c < 32; ++c)
    s += nt_load(&part[(((size_t)j * nch + r * 32 + c) * NB + b) * ND + d]);
  part2[(((size_t)j * RG + r) * NB + b) * ND + d] = s;
}

// ---------- final reduce + squash + vsum/out ----------
__global__ __launch_bounds__(1024) void kern_squash(const float* __restrict__ part2,
                                                    float* __restrict__ vsum,
                                                    float* __restrict__ out,
                                                    int mode, int RG) {
  const int j = blockIdx.x;
  const int t = threadIdx.x;
  const int b = t >> 5;
  const int d = t & 31;
  float s = 0.f;
  for (int r = 0; r < RG; ++r)
    s += nt_load(&part2[(((size_t)j * RG + r) * NB + b) * ND + d]);

  __shared__ float sl[32][33];
  __shared__ float fb[32];
  sl[b][d] = s;
  __syncthreads();
  if (t < 32) {
    float n2 = 0.f;
#pragma unroll
    for (int dd = 0; dd < ND; ++dd) { const float x = sl[t][dd]; n2 += x * x; }
    fb[t] = n2 / ((1.0f + n2) * sqrtf(n2 + EPSF));
  }
  __syncthreads();
  const float v = s * fb[b];
  const int idx = (b * NJ + j) * ND + d;
  if (mode == 0)      vsum[idx] = v;        // iter0: vsum := v0 (never read-before-write)
  else if (mode == 1) vsum[idx] += v;       // iter1: vsum := v0+v1
  else                out[idx] = v;         // iter2: final output [B,J,D]
}

extern "C" void kernel_launch(void* const* d_in, const int* in_sizes, int n_in,
                              void* d_out, int out_size, void* d_ws, size_t ws_size,
                              hipStream_t stream) {
  const float* inp = (const float*)d_in[0];
  const float* W   = (const float*)d_in[1];
  // defensive: inputs is 1M elems, W is 33.5M elems
  if (n_in >= 2 && in_sizes[0] > in_sizes[1]) { const float* tmp = inp; inp = W; W = tmp; }
  float* out = (float*)d_out;
  char* ws = (char*)d_ws;
  (void)out_size;

  // proven layout: Xt@0 (2MB) | part (nch*128KB) | vsum (128KB) | part2 (RG*128KB)
  int nch = 256;
  while (nch > 32 &&
         (size_t)(2u << 20) + (size_t)nch * 131072u + 131072u +
             (size_t)(nch / 32) * 131072u > ws_size)
    nch >>= 1;
  const int ipb = NI / nch;
  const int RG = nch / 32;

  unsigned short* Xt = (unsigned short*)ws;
  float* part  = (float*)(ws + (2u << 20));
  float* vsum  = part + (size_t)NJ * nch * NB * ND;   // full part extent
  float* part2 = vsum + (size_t)NB * NJ * ND;         // after vsum

  kern_prep<<<1024, 256, 0, stream>>>(inp, Xt);

  // iter 0: uniform c = 1/32
  kern_fused<true><<<nch, 512, 0, stream>>>(W, Xt, nullptr, part, ipb, nch);
  kern_reduce1<<<32 * RG, 1024, 0, stream>>>(part, part2, nch, RG);
  kern_squash<<<32, 1024, 0, stream>>>(part2, vsum, out, 0, RG);

  // iter 1
  kern_fused<false><<<nch, 512, 0, stream>>>(W, Xt, vsum, part, ipb, nch);
  kern_reduce1<<<32 * RG, 1024, 0, stream>>>(part, part2, nch, RG);
  kern_squash<<<32, 1024, 0, stream>>>(part2, vsum, out, 1, RG);

  // iter 2
  kern_fused<false><<<nch, 512, 0, stream>>>(W, Xt, vsum, part, ipb, nch);
  kern_reduce1<<<32 * RG, 1024, 0, stream>>>(part, part2, nch, RG);
  kern_squash<<<32, 1024, 0, stream>>>(part2, vsum, out, 2, RG);
}

// Round 13
// 152.450 us; speedup vs baseline: 1.5483x; 1.0640x over previous
//
#include <hip/hip_runtime.h>

#define NB 32
#define NI 2048
#define NP 16
#define NJ 32
#define ND 32
#define EPSF 1e-7f

typedef __attribute__((ext_vector_type(8))) short bf16x8;
typedef __attribute__((ext_vector_type(16))) float f32x16;
typedef __attribute__((ext_vector_type(4))) float f32x4;

static __device__ __forceinline__ unsigned cvt_pk_bf16(float lo, float hi) {
  unsigned r;
  asm("v_cvt_pk_bf16_f32 %0, %1, %2" : "=v"(r) : "v"(lo), "v"(hi));
  return r;
}

static __device__ __forceinline__ f32x16 mfma_bf16(bf16x8 a, bf16x8 b, f32x16 c) {
  return __builtin_amdgcn_mfma_f32_32x32x16_bf16(a, b, c, 0, 0, 0);
}

static __device__ __forceinline__ float nt_load(const float* p) {
  return __builtin_nontemporal_load(p);   // read + evict hint (dead-after-read only)
}

// Raw W row gather for one (i,j): 8 f32 at stride ND. Loads issue HERE;
// conversion happens at use (pack_wfrag) so prefetched loads overlap compute.
struct wraw { float f[8]; };
static __device__ __forceinline__ wraw load_wraw(const float* __restrict__ W,
                                                 int i, int j, int h, int d) {
  const float* wp = W + (((size_t)i * NJ + j) * NP + h * 8) * ND + d;
  wraw r;
#pragma unroll
  for (int e = 0; e < 8; ++e) r.f[e] = wp[e * ND];
  return r;
}
// A operand: lane l: m = d = l&31, k = p = 8*(l>>5) + e
static __device__ __forceinline__ bf16x8 pack_wfrag(const wraw& r) {
  union { unsigned u[4]; bf16x8 v; } wf;
  wf.u[0] = cvt_pk_bf16(r.f[0], r.f[1]);
  wf.u[1] = cvt_pk_bf16(r.f[2], r.f[3]);
  wf.u[2] = cvt_pk_bf16(r.f[4], r.f[5]);
  wf.u[3] = cvt_pk_bf16(r.f[6], r.f[7]);
  return wf.v;
}

// B operand: lane l: k = p = 8*(l>>5)+e, n = b = l&31
static __device__ __forceinline__ bf16x8 load_xfrag(const unsigned short* __restrict__ Xt,
                                                    int i, int b, int h) {
  return *(const bf16x8*)(Xt + ((size_t)i * NB + b) * NP + h * 8);
}

// ---------- prep: inputs[b][i][p] (f32) -> Xt[i][b][p] (bf16) ----------
__global__ __launch_bounds__(256) void kern_prep(const float* __restrict__ in,
                                                 unsigned short* __restrict__ Xt) {
  const int t = blockIdx.x * 256 + threadIdx.x;   // 262144 threads, 4 elems each
  const int rest = t >> 2;                        // b*NI + i
  const int p4 = (t & 3) * 4;
  const int i = rest & (NI - 1);
  const int b = rest >> 11;
  f32x4 x = *(const f32x4*)(in + (size_t)rest * NP + p4);
  uint2 v;
  v.x = cvt_pk_bf16(x[0], x[1]);
  v.y = cvt_pk_bf16(x[2], x[3]);
  *(uint2*)(Xt + ((size_t)i * NB + b) * NP + p4) = v;
}

// ---------- fused routing pass over an i-chunk ----------
// 512 threads = 8 waves; wave w owns j = w*4 + t (t=0..3); block ch covers ipb i's.
// R13: SOFTWARE PIPELINE — prefetch next ii's raw W (f32) + X frag before the
// barrier section; convert at use. The 2 barriers/ii previously exposed full
// memory latency at 2 waves/EU (R11: VALUBusy 1.7%, 18% occupancy).
// sacc stays pure-MFMA C/D (re-MFMA with c-scaled B) per R12.
template <bool UNIFORM>
__global__ __attribute__((amdgpu_waves_per_eu(2, 2)))
__launch_bounds__(512) void kern_fused(const float* __restrict__ W,
                                       const unsigned short* __restrict__ Xt,
                                       const float* __restrict__ vsum,
                                       float* __restrict__ part,
                                       int ipb, int nch) {
  const int tid = threadIdx.x;
  const int w = tid >> 6;
  const int lane = tid & 63;
  const int b = lane & 31;
  const int h = lane >> 5;
  const int ch = blockIdx.x;
  const int i0 = ch * ipb;

  // register-resident vsum fragment: vs[t][q][e] = vsum[b][j=w*4+t][8q + 4h + e]
  f32x4 vs[4][4];
  if (!UNIFORM) {
#pragma unroll
    for (int t = 0; t < 4; ++t) {
      const int j = w * 4 + t;
#pragma unroll
      for (int q = 0; q < 4; ++q)
        vs[t][q] = *(const f32x4*)(vsum + ((size_t)b * NJ + j) * ND + q * 8 + h * 4);
    }
  }

  f32x16 sacc[4] = {};
  __shared__ float lgt[NJ][33];

  // pipeline prologue: loads for ii = 0
  wraw wr[4];
  bf16x8 xf;
#pragma unroll
  for (int t = 0; t < 4; ++t) wr[t] = load_wraw(W, i0, w * 4 + t, h, b);
  xf = load_xfrag(Xt, i0, b, h);

  for (int ii = 0; ii < ipb; ++ii) {
    const int i = i0 + ii;
    // issue next iteration's loads NOW (overlap with everything below).
    const int inext = (ii + 1 < ipb) ? i + 1 : i;   // clamped: harmless re-read
    wraw wrn[4];
#pragma unroll
    for (int t = 0; t < 4; ++t) wrn[t] = load_wraw(W, inext, w * 4 + t, h, b);
    const bf16x8 xfn = load_xfrag(Xt, inext, b, h);

    // convert current W to bf16 fragments
    bf16x8 wf[4];
#pragma unroll
    for (int t = 0; t < 4; ++t) wf[t] = pack_wfrag(wr[t]);

    if (UNIFORM) {
#pragma unroll
      for (int t = 0; t < 4; ++t) sacc[t] = mfma_bf16(wf[t], xf, sacc[t]);
    } else {
      // unpack this lane's 8 bf16 x-values to f32 (for the c-scaled re-pack)
      union { bf16x8 v; unsigned short s[8]; } xu; xu.v = xf;
      float xf32[8];
#pragma unroll
      for (int e = 0; e < 8; ++e)
        xf32[e] = __uint_as_float((unsigned)xu.s[e] << 16);

      float lg[4];
#pragma unroll
      for (int t = 0; t < 4; ++t) {
        f32x16 z = {};
        const f32x16 um = mfma_bf16(wf[t], xf, z);   // transient: dies before barrier
        float p = 0.f;
#pragma unroll
        for (int r = 0; r < 16; ++r)
          p += um[r] * vs[t][r >> 2][r & 3];         // d(r) = (r&3) + 8*(r>>2) + 4h
        p += __shfl_xor(p, 32);                      // add partner half's 16 d's
        lg[t] = p;
      }
      if (h == 0) {
#pragma unroll
        for (int t = 0; t < 4; ++t) lgt[w * 4 + t][b] = lg[t];
      }
      __syncthreads();
      // per-(b,i) softmax over j (each thread reduces its own b's column)
      float mx = -3.0e38f;
#pragma unroll
      for (int jj = 0; jj < NJ; ++jj) mx = fmaxf(mx, lgt[jj][b]);
      float den = 0.f;
#pragma unroll
      for (int jj = 0; jj < NJ; ++jj) den += expf(lgt[jj][b] - mx);
      const float inv = 1.0f / den;
#pragma unroll
      for (int t = 0; t < 4; ++t) {
        const float c = expf(lg[t] - mx) * inv;
        union { unsigned u[4]; bf16x8 v; } xc;
#pragma unroll
        for (int e = 0; e < 4; ++e)
          xc.u[e] = cvt_pk_bf16(xf32[2 * e] * c, xf32[2 * e + 1] * c);
        sacc[t] = mfma_bf16(wf[t], xc.v, sacc[t]);   // sacc stays pure-MFMA
      }
      __syncthreads();   // protect lgt before next i overwrites it
    }

    // rotate pipeline registers
#pragma unroll
    for (int t = 0; t < 4; ++t) wr[t] = wrn[t];
    xf = xfn;
  }

  // epilogue: 4 contiguous f32x4 stores per (t) instead of 16 scattered dwords.
#pragma unroll
  for (int t = 0; t < 4; ++t) {
    const int j = w * 4 + t;
    float* base = &part[(((size_t)j * nch + ch) * NB + b) * ND];
#pragma unroll
    for (int rq = 0; rq < 4; ++rq) {
      f32x4 v4;
#pragma unroll
      for (int e = 0; e < 4; ++e) {
        const float val = UNIFORM ? sacc[t][rq * 4 + e] * (1.0f / 32.0f)
                                  : sacc[t][rq * 4 + e];
        v4[e] = val;
      }
      *(f32x4*)(base + rq * 8 + 4 * h) = v4;   // d = 8*rq + 4h + e
    }
  }
}

// ---------- stage-1 reduce: 32-chunk groups -> part2[j][r][b][d] ----------
// nt_load: part is dead after this read -> evict-hint frees L2/L3 for W.
__global__ __launch_bounds__(1024) void kern_reduce1(const float* __restrict__ part,
                                                     float* __restrict__ part2,
                                                     int nch, int RG) {
  const int j = blockIdx.x / RG;
  const int r = blockIdx.x % RG;
  const int t = threadIdx.x;
  const int b = t >> 5;
  const int d = t & 31;
  float s = 0.f;
#pragma unroll 4
  for (int c = 0; c < 32; ++c)
    s += nt_load(&part[(((size_t)j * nch + r * 32 + c) * NB + b) * ND + d]);
  part2[(((size_t)j * RG + r) * NB + b) * ND + d] = s;
}

// ---------- final reduce + squash + vsum/out ----------
__global__ __launch_bounds__(1024) void kern_squash(const float* __restrict__ part2,
                                                    float* __restrict__ vsum,
                                                    float* __restrict__ out,
                                                    int mode, int RG) {
  const int j = blockIdx.x;
  const int t = threadIdx.x;
  const int b = t >> 5;
  const int d = t & 31;
  float s = 0.f;
  for (int r = 0; r < RG; ++r)
    s += nt_load(&part2[(((size_t)j * RG + r) * NB + b) * ND + d]);

  __shared__ float sl[32][33];
  __shared__ float fb[32];
  sl[b][d] = s;
  __syncthreads();
  if (t < 32) {
    float n2 = 0.f;
#pragma unroll
    for (int dd = 0; dd < ND; ++dd) { const float x = sl[t][dd]; n2 += x * x; }
    fb[t] = n2 / ((1.0f + n2) * sqrtf(n2 + EPSF));
  }
  __syncthreads();
  const float v = s * fb[b];
  const int idx = (b * NJ + j) * ND + d;
  if (mode == 0)      vsum[idx] = v;        // iter0: vsum := v0 (never read-before-write)
  else if (mode == 1) vsum[idx] += v;       // iter1: vsum := v0+v1
  else                out[idx] = v;         // iter2: final output [B,J,D]
}

extern "C" void kernel_launch(void* const* d_in, const int* in_sizes, int n_in,
                              void* d_out, int out_size, void* d_ws, size_t ws_size,
                              hipStream_t stream) {
  const float* inp = (const float*)d_in[0];
  const float* W   = (const float*)d_in[1];
  // defensive: inputs is 1M elems, W is 33.5M elems
  if (n_in >= 2 && in_sizes[0] > in_sizes[1]) { const float* tmp = inp; inp = W; W = tmp; }
  float* out = (float*)d_out;
  char* ws = (char*)d_ws;
  (void)out_size;

  // proven layout: Xt@0 (2MB) | part (nch*128KB) | vsum (128KB) | part2 (RG*128KB)
  int nch = 256;
  while (nch > 32 &&
         (size_t)(2u << 20) + (size_t)nch * 131072u + 131072u +
             (size_t)(nch / 32) * 131072u > ws_size)
    nch >>= 1;
  const int ipb = NI / nch;
  const int RG = nch / 32;

  unsigned short* Xt = (unsigned short*)ws;
  float* part  = (float*)(ws + (2u << 20));
  float* vsum  = part + (size_t)NJ * nch * NB * ND;   // full part extent
  float* part2 = vsum + (size_t)NB * NJ * ND;         // after vsum

  kern_prep<<<1024, 256, 0, stream>>>(inp, Xt);

  // iter 0: uniform c = 1/32
  kern_fused<true><<<nch, 512, 0, stream>>>(W, Xt, nullptr, part, ipb, nch);
  kern_reduce1<<<32 * RG, 1024, 0, stream>>>(part, part2, nch, RG);
  kern_squash<<<32, 1024, 0, stream>>>(part2, vsum, out, 0, RG);

  // iter 1
  kern_fused<false><<<nch, 512, 0, stream>>>(W, Xt, vsum, part, ipb, nch);
  kern_reduce1<<<32 * RG, 1024, 0, stream>>>(part, part2, nch, RG);
  kern_squash<<<32, 1024, 0, stream>>>(part2, vsum, out, 1, RG);

  // iter 2
  kern_fused<false><<<nch, 512, 0, stream>>>(W, Xt, vsum, part, ipb, nch);
  kern_reduce1<<<32 * RG, 1024, 0, stream>>>(part, part2, nch, RG);
  kern_squash<<<32, 1024, 0, stream>>>(part2, vsum, out, 2, RG);
}